// Round 12
// baseline (2045.890 us; speedup 1.0000x reference)
//
#include <hip/hip_runtime.h>
#include <cstdint>
#include <cstddef>

#define F_CH 76
#define T_LEN 4096
#define B_TOT 64
#define C_CLS 15
#define NSTEP 8

// ---- rk4 1-step kernel geometry (3-wave blocks for multi-block residency) ----
#define W_OUT  24            // output t per block (halo 4 each side, 1 RK4 step)
#define HALO   4
#define NBT    171           // ceil(4096/24)
#define NKB    5             // k-blocks of 16 (ci padded to 80)
#define WSTR   88            // weight row stride in bf16 (global wpb)
#define SST    128           // s_lds row stride in bf16 (16 slots of 8; XOR-bijective)
#define SROWS  34            // 32 compute rows + 2 halo
#define TPB    192           // 3 waves: ct 0..2, one 32-row t-tile each
#define HP     80            // h global row pitch (floats)

#define C2LOG2E 2.8853900817779268f   // 2*log2(e)

typedef __attribute__((ext_vector_type(8)))  __bf16 bf16x8;
typedef __attribute__((ext_vector_type(4)))  __bf16 bf16x4;
typedef __attribute__((ext_vector_type(16))) float  f32x16;

// swizzled element offset of 8-elem slot `v` (0..15) in LDS row `r`; bijective
__device__ __forceinline__ int sw_off(int r, int v) {
    return r * SST + (((v) ^ (r & 7)) << 3);
}

// ---------------- pad-copy: x [B,T,76] -> h [Bc,T,80] (cols 76..79 zero) ----------------
__global__ __launch_bounds__(256) void pad_copy_kernel(
    const float* __restrict__ x, float* __restrict__ h, int b0)
{
    int bl = blockIdx.y;
    int q  = blockIdx.x * 256 + threadIdx.x;      // quad index within batch
    int t  = q / 20, c4 = (q - t * 20) * 4;
    float4 v = {0.f, 0.f, 0.f, 0.f};
    if (c4 < F_CH)
        v = *(const float4*)(x + ((size_t)(b0 + bl) * T_LEN + t) * F_CH + c4);
    *(float4*)(h + ((size_t)bl * T_LEN + t) * HP + c4) = v;
}

// ---- weight prep: cw [76][76][3] f32 -> wpb [3][96][WSTR] bf16 (zero-padded) ----
__global__ __launch_bounds__(256) void wprep_kernel(
    const float* __restrict__ cw, __bf16* __restrict__ wpb)
{
    int idx = blockIdx.x * 256 + threadIdx.x;
    if (idx >= 3 * 96 * WSTR) return;
    int tap = idx / (96 * WSTR);
    int rem = idx - tap * 96 * WSTR;
    int c = rem / WSTR, ci = rem - c * WSTR;
    float v = 0.0f;
    if (c < F_CH && ci < F_CH) v = cw[((size_t)c * F_CH + ci) * 3 + tap];
    wpb[idx] = (__bf16)v;
}

// ---------- one RK4 step: hout = h + dt/6 (k1+2k2+2k3+k4) on valid window ----------
__global__ __launch_bounds__(TPB, 4) void rk4_step_kernel(
    const float* __restrict__ hin, float* __restrict__ hout,
    const __bf16* __restrict__ wpb, const float* __restrict__ cb)
{
    __shared__ __bf16 s_lds[2][SROWS * SST];

    const int b    = blockIdx.y;
    const int T0   = blockIdx.x * W_OUT;
    const int tid  = threadIdx.x;
    const int lane = tid & 63;
    const int l31  = lane & 31;
    const int l5   = lane >> 5;          // 0..1
    const int ct   = tid >> 6;           // c-tile 0..2

    const int  rb  = l31;                // compute row 0..31
    const int  tg  = T0 - HALO + rb;
    const bool tok = (tg >= 0 && tg < T_LEN);

    // zero the 4 halo rows (2 buffers x rows {0, SROWS-1} x 64 dwords)
    {
        int i0 = tid;            // 0..191
        int i1 = tid + 192;      // 192..255 used partially
        int bi = i0 >> 7, rr = (i0 >> 6) & 1, c = i0 & 63;
        ((uint32_t*)&s_lds[bi][(rr ? (SROWS - 1) : 0) * SST])[c] = 0u;
        if (i1 < 256) {
            int bj = i1 >> 7, rs = (i1 >> 6) & 1, d = i1 & 63;
            ((uint32_t*)&s_lds[bj][(rs ? (SROWS - 1) : 0) * SST])[d] = 0u;
        }
    }

    // ---- load h (f32): hn = f32 accumulator, hpk = packed bf16 stage base ----
    float  hn[16];
    bf16x4 hpk[4];
    const float* hb = hin + (size_t)b * T_LEN * HP;
    #pragma unroll
    for (int q = 0; q < 4; ++q) {
        int c0 = ct * 32 + l5 * 4 + q * 8;
        float4 v = {0.f, 0.f, 0.f, 0.f};
        if (tok && c0 < HP) v = *(const float4*)(hb + (size_t)tg * HP + c0);
        hn[q*4+0]=v.x; hn[q*4+1]=v.y; hn[q*4+2]=v.z; hn[q*4+3]=v.w;
        hpk[q][0]=(__bf16)v.x; hpk[q][1]=(__bf16)v.y;
        hpk[q][2]=(__bf16)v.z; hpk[q][3]=(__bf16)v.w;
    }

    // ---- bias per lane-element (acc C-init); pad channels get 0 ----
    float cbs[16];
    #pragma unroll
    for (int q = 0; q < 4; ++q)
        #pragma unroll
        for (int j = 0; j < 4; ++j) {
            int c = ct * 32 + l5 * 4 + q * 8 + j;
            cbs[q*4+j] = (c < F_CH) ? cb[c] : 0.0f;
        }

    // ---- A fragments: 3 taps x 5 k-blocks, registers, from global (L2) ----
    bf16x8 afr[3][NKB];
    #pragma unroll
    for (int tap = 0; tap < 3; ++tap)
        #pragma unroll
        for (int kb = 0; kb < NKB; ++kb)
            afr[tap][kb] = *(const bf16x8*)&wpb[((size_t)tap * 96 + ct * 32 + l31) * WSTR
                                                + kb * 16 + l5 * 8];

    // ---- write stage-1 input = hpk into buffer 0 (swizzled slots) ----
    #pragma unroll
    for (int q = 0; q < 4; ++q) {
        int c0 = ct * 32 + l5 * 4 + q * 8;
        if (c0 < HP)
            *(bf16x4*)&s_lds[0][sw_off(rb + 1, ct * 4 + q) + l5 * 4] = hpk[q];
    }

    const float dt = 0.125f;

    #pragma unroll 1
    for (int e = 0; e < 4; ++e) {
        const float we   = (e == 0 || e == 3) ? dt / 6.0f : dt / 3.0f;
        const float al   = (e == 2) ? dt : 0.5f * dt;
        const float al_t = tok ? al : 0.0f;

        __syncthreads();   // stage writes for eval e complete

        const __bf16* sb = s_lds[e & 1];
        f32x16 a0;
        #pragma unroll
        for (int i = 0; i < 16; ++i) a0[i] = cbs[i];   // bias as C-init
        #pragma unroll
        for (int tap = 0; tap < 3; ++tap) {
            #pragma unroll
            for (int kb = 0; kb < NKB; ++kb) {
                bf16x8 bf = *(const bf16x8*)&sb[sw_off(rb + tap, kb * 2 + l5)];
                a0 = __builtin_amdgcn_mfma_f32_32x32x16_bf16(afr[tap][kb], bf, a0, 0, 0, 0);
            }
        }

        // epilogue: kv = tanh(acc) = 1 - 2/(exp2(acc*2log2e)+1)
        __bf16* sw = s_lds[(e + 1) & 1];
        #pragma unroll
        for (int q = 0; q < 4; ++q) {
            int c0 = ct * 32 + l5 * 4 + q * 8;
            if (c0 >= HP) continue;        // pad channels: never read
            bf16x4 p;
            #pragma unroll
            for (int j = 0; j < 4; ++j) {
                float y  = a0[q*4+j] * C2LOG2E;
                float ex = __builtin_amdgcn_exp2f(y);
                float kv = fmaf(-2.0f, __builtin_amdgcn_rcpf(ex + 1.0f), 1.0f);
                hn[q*4+j] = fmaf(we, kv, hn[q*4+j]);
                if (e < 3) p[j] = (__bf16)fmaf(al_t, kv, (float)hpk[q][j]);
            }
            if (e < 3)
                *(bf16x4*)&sw[sw_off(rb + 1, ct * 4 + q) + l5 * 4] = p;
        }
    }

    // ---- store hnext (valid rows [HALO, HALO+W_OUT)) ----
    if (rb >= HALO && rb < HALO + W_OUT && tg < T_LEN) {
        float* ho = hout + ((size_t)b * T_LEN + tg) * HP;
        #pragma unroll
        for (int q = 0; q < 4; ++q) {
            int c0 = ct * 32 + l5 * 4 + q * 8;
            if (c0 < HP) {
                float4 v;
                v.x = hn[q*4+0]; v.y = hn[q*4+1];
                v.z = hn[q*4+2]; v.w = hn[q*4+3];
                *(float4*)(ho + c0) = v;
            }
        }
    }
}

// ------------- final linear: out[b,t,c] = sum_f h[t][f]*fw[c,f] + fb[c] -------------
__global__ __launch_bounds__(256) void final_kernel(
    const float* __restrict__ h, const float* __restrict__ fw,
    const float* __restrict__ fb, float* __restrict__ out, int b0)
{
    int bl = blockIdx.y;
    int t  = blockIdx.x * 256 + threadIdx.x;
    const float* hr = h + ((size_t)bl * T_LEN + t) * HP;
    float acc[C_CLS];
#pragma unroll
    for (int c = 0; c < C_CLS; ++c) acc[c] = fb[c];
#pragma unroll
    for (int qf = 0; qf < 19; ++qf) {
        float4 v = *(const float4*)(hr + qf * 4);
#pragma unroll
        for (int c = 0; c < C_CLS; ++c) {
            const float* w = fw + c * F_CH + qf * 4;
            acc[c] = fmaf(w[0], v.x, acc[c]);
            acc[c] = fmaf(w[1], v.y, acc[c]);
            acc[c] = fmaf(w[2], v.z, acc[c]);
            acc[c] = fmaf(w[3], v.w, acc[c]);
        }
    }
    float* ob = out + ((size_t)(b0 + bl) * T_LEN + t) * C_CLS;
#pragma unroll
    for (int c = 0; c < C_CLS; ++c) ob[c] = acc[c];
}

extern "C" void kernel_launch(void* const* d_in, const int* in_sizes, int n_in,
                              void* d_out, int out_size, void* d_ws, size_t ws_size,
                              hipStream_t stream)
{
    const float* x  = (const float*)d_in[0];
    const float* cw = (const float*)d_in[1];
    const float* cb = (const float*)d_in[2];
    const float* fw = (const float*)d_in[3];
    const float* fb = (const float*)d_in[4];
    float* out = (float*)d_out;

    const size_t FT = (size_t)T_LEN * HP;            // floats per batch plane

    __bf16* WPB = (__bf16*)d_ws;
    const size_t wpbFloats = 12800;                  // 3*96*88 bf16, padded
    float* planes = (float*)d_ws + wpbFloats;

    size_t planeBytes = 2 * FT * sizeof(float);
    size_t avail = ws_size - wpbFloats * sizeof(float);
    int Bc = (int)(avail / planeBytes);
    if (Bc > B_TOT) Bc = B_TOT;
    if (Bc < 1) Bc = 1;

    float* H0 = planes;
    float* H1 = H0 + (size_t)Bc * FT;

    wprep_kernel<<<(3 * 96 * WSTR + 255) / 256, 256, 0, stream>>>(cw, WPB);

    for (int b0 = 0; b0 < B_TOT; b0 += Bc) {
        int bc = (B_TOT - b0 < Bc) ? (B_TOT - b0) : Bc;

        dim3 gP(T_LEN * 20 / 256, bc);
        pad_copy_kernel<<<gP, 256, 0, stream>>>(x, H0, b0);

        float* hcur = H0;
        float* hnxt = H1;
        dim3 gR(NBT, bc);
        for (int st = 0; st < NSTEP; ++st) {
            rk4_step_kernel<<<gR, TPB, 0, stream>>>(hcur, hnxt, WPB, cb);
            float* tmp = hcur; hcur = hnxt; hnxt = tmp;
        }

        dim3 gF(T_LEN / 256, bc);
        final_kernel<<<gF, 256, 0, stream>>>(hcur, fw, fb, out, b0);
    }
}

// Round 13
// 816.033 us; speedup vs baseline: 2.5071x; 2.5071x over previous
//
#include <hip/hip_runtime.h>
#include <cstdint>
#include <cstddef>

#define F_CH 76
#define T_LEN 4096
#define B_TOT 64
#define C_CLS 15
#define NSTEP 8

// ---- rk4 fused-2-step kernel geometry ----
#define W_OUT  112           // output t per block (halo 8 each side, 2 RK4 steps)
#define HALO2  8
#define NBT    37            // ceil(4096/112)
#define NKB    5             // k-blocks of 16 (ci padded to 80)
#define WSTR   88            // weight row stride in bf16 (global wpb)
#define SST    128           // s_lds row stride in bf16 (16 slots of 8; XOR-bijective)
#define SROWS  130           // 128 compute rows + 2 halo
#define TPB    768           // 12 waves: (ct 0..2) x (tq 0..3)
#define HP     80            // h global row pitch (floats)

#define C2LOG2E 2.8853900817779268f   // 2*log2(e)

typedef __attribute__((ext_vector_type(8)))  __bf16 bf16x8;
typedef __attribute__((ext_vector_type(4)))  __bf16 bf16x4;
typedef __attribute__((ext_vector_type(16))) float  f32x16;

// swizzled element offset of 8-elem slot `v` (0..15) in LDS row `r`.
// bijective: slot^(r&15) stays in [0,16). Fixed slot maps to 16 distinct
// positions over 16 consecutive rows -> 2 rows/position over a 32-row wave
// access = free 2-way regime (vs 4-way with &7).
__device__ __forceinline__ int sw_off(int r, int v) {
    return r * SST + (((v) ^ (r & 15)) << 3);
}

// ---------------- pad-copy: x [B,T,76] -> h [Bc,T,80] (cols 76..79 zero) ----------------
__global__ __launch_bounds__(256) void pad_copy_kernel(
    const float* __restrict__ x, float* __restrict__ h, int b0)
{
    int bl = blockIdx.y;
    int q  = blockIdx.x * 256 + threadIdx.x;      // quad index within batch
    int t  = q / 20, c4 = (q - t * 20) * 4;
    float4 v = {0.f, 0.f, 0.f, 0.f};
    if (c4 < F_CH)
        v = *(const float4*)(x + ((size_t)(b0 + bl) * T_LEN + t) * F_CH + c4);
    *(float4*)(h + ((size_t)bl * T_LEN + t) * HP + c4) = v;
}

// ---- weight prep: cw [76][76][3] f32 -> wpb [3][96][WSTR] bf16 (zero-padded) ----
__global__ __launch_bounds__(256) void wprep_kernel(
    const float* __restrict__ cw, __bf16* __restrict__ wpb)
{
    int idx = blockIdx.x * 256 + threadIdx.x;
    if (idx >= 3 * 96 * WSTR) return;
    int tap = idx / (96 * WSTR);
    int rem = idx - tap * 96 * WSTR;
    int c = rem / WSTR, ci = rem - c * WSTR;
    float v = 0.0f;
    if (c < F_CH && ci < F_CH) v = cw[((size_t)c * F_CH + ci) * 3 + tap];
    wpb[idx] = (__bf16)v;
}

// ---------- fused 2x RK4 steps: hout = RK4(RK4(hin)) on valid window ----------
__global__ __launch_bounds__(TPB, 3) void rk4_step2_kernel(
    const float* __restrict__ hin, float* __restrict__ hout,
    const __bf16* __restrict__ wpb, const float* __restrict__ cb)
{
    __shared__ __bf16 s_lds[2][SROWS * SST];
    __shared__ float  cb_lds[96];     // pre-scaled bias: cb * 2log2e (pad = 0)

    const int b    = blockIdx.y;
    const int T0   = blockIdx.x * W_OUT;
    const int tid  = threadIdx.x;
    const int lane = tid & 63;
    const int l31  = lane & 31;
    const int l5   = lane >> 5;          // 0..1
    const int wv   = tid >> 6;           // 0..11
    const int ct   = wv >> 2;            // c-tile 0..2
    const int tq   = wv & 3;             // t-tile 0..3

    const int  rb  = tq * 32 + l31;      // row base 0..127
    const int  tg  = T0 - HALO2 + rb;
    const bool tok = (tg >= 0 && tg < T_LEN);

    // zero the 4 halo rows (2 buffers x rows {0, SROWS-1} x 64 dwords); scaled bias
    if (tid < 256) {
        int bi = tid / 128, rr = (tid % 128) / 64, c = tid % 64;
        ((uint32_t*)&s_lds[bi][(rr ? (SROWS - 1) : 0) * SST])[c] = 0u;
    }
    if (tid < 96) cb_lds[tid] = (tid < F_CH) ? cb[tid] * C2LOG2E : 0.0f;

    // ---- load h (f32): hn = f32 accumulator, hpk = packed bf16 stage base ----
    float  hn[16];
    bf16x4 hpk[4];
    const float* hb = hin + (size_t)b * T_LEN * HP;
    #pragma unroll
    for (int q = 0; q < 4; ++q) {
        int c0 = ct * 32 + l5 * 4 + q * 8;
        float4 v = {0.f, 0.f, 0.f, 0.f};
        if (tok && c0 < HP) v = *(const float4*)(hb + (size_t)tg * HP + c0);
        hn[q*4+0]=v.x; hn[q*4+1]=v.y; hn[q*4+2]=v.z; hn[q*4+3]=v.w;
        hpk[q][0]=(__bf16)v.x; hpk[q][1]=(__bf16)v.y;
        hpk[q][2]=(__bf16)v.z; hpk[q][3]=(__bf16)v.w;
    }

    // ---- A fragments: 3 taps x 5 k-blocks, registers, from global (L2) ----
    bf16x8 afr[3][NKB];
    #pragma unroll
    for (int tap = 0; tap < 3; ++tap)
        #pragma unroll
        for (int kb = 0; kb < NKB; ++kb)
            afr[tap][kb] = *(const bf16x8*)&wpb[((size_t)tap * 96 + ct * 32 + l31) * WSTR
                                                + kb * 16 + l5 * 8];

    const float dt = 0.125f;

    #pragma unroll 1
    for (int st = 0; st < 2; ++st) {
        // ---- write stage-1 input = hpk into buffer 0 (swizzled slots) ----
        #pragma unroll
        for (int q = 0; q < 4; ++q) {
            int c0 = ct * 32 + l5 * 4 + q * 8;
            if (c0 < HP)
                *(bf16x4*)&s_lds[0][sw_off(rb + 1, ct * 4 + q) + l5 * 4] = hpk[q];
        }
        __syncthreads();

        #pragma unroll 1
        for (int e = 0; e < 4; ++e) {
            const float we   = (e == 0 || e == 3) ? dt / 6.0f : dt / 3.0f;
            const float al   = (e == 2) ? dt : 0.5f * dt;
            const float al_t = tok ? al : 0.0f;

            const __bf16* sb = s_lds[e & 1];
            f32x16 a0 = {};
            #pragma unroll
            for (int tap = 0; tap < 3; ++tap) {
                #pragma unroll
                for (int kb = 0; kb < NKB; ++kb) {
                    bf16x8 bf = *(const bf16x8*)&sb[sw_off(rb + tap, kb * 2 + l5)];
                    a0 = __builtin_amdgcn_mfma_f32_32x32x16_bf16(afr[tap][kb], bf, a0, 0, 0, 0);
                }
            }

            // epilogue: kv = tanh(acc+bias) = 1 - 2/(exp2((acc+b)*2log2e)+1)
            __bf16* sw = s_lds[(e + 1) & 1];
            #pragma unroll
            for (int q = 0; q < 4; ++q) {
                int c0 = ct * 32 + l5 * 4 + q * 8;
                if (c0 >= HP) continue;        // pad channels: never read
                bf16x4 p;
                #pragma unroll
                for (int j = 0; j < 4; ++j) {
                    float y  = fmaf(a0[q*4+j], C2LOG2E, cb_lds[c0 + j]);
                    float ex = __builtin_amdgcn_exp2f(y);
                    float kv = fmaf(-2.0f, __builtin_amdgcn_rcpf(ex + 1.0f), 1.0f);
                    hn[q*4+j] = fmaf(we, kv, hn[q*4+j]);
                    if (e < 3) p[j] = (__bf16)fmaf(al_t, kv, (float)hpk[q][j]);
                }
                if (e < 3)
                    *(bf16x4*)&sw[sw_off(rb + 1, ct * 4 + q) + l5 * 4] = p;
            }
            if (e < 3) __syncthreads();
        }

        // ---- between steps: h <- (tok ? hn : 0); repack ----
        if (st == 0) {
            #pragma unroll
            for (int i = 0; i < 16; ++i) hn[i] = tok ? hn[i] : 0.0f;
            #pragma unroll
            for (int q = 0; q < 4; ++q)
                #pragma unroll
                for (int j = 0; j < 4; ++j) hpk[q][j] = (__bf16)hn[q*4+j];
            __syncthreads();   // all e=3 reads (buf1) complete before buf0 overwrite
        }
    }

    // ---- store h2 (valid rows [HALO2, HALO2+W_OUT)) ----
    if (rb >= HALO2 && rb < HALO2 + W_OUT && tg < T_LEN) {
        float* ho = hout + ((size_t)b * T_LEN + tg) * HP;
        #pragma unroll
        for (int q = 0; q < 4; ++q) {
            int c0 = ct * 32 + l5 * 4 + q * 8;
            if (c0 < HP) {
                float4 v;
                v.x = hn[q*4+0]; v.y = hn[q*4+1];
                v.z = hn[q*4+2]; v.w = hn[q*4+3];
                *(float4*)(ho + c0) = v;
            }
        }
    }
}

// ------------- final linear: out[b,t,c] = sum_f h[t][f]*fw[c,f] + fb[c] -------------
__global__ __launch_bounds__(256) void final_kernel(
    const float* __restrict__ h, const float* __restrict__ fw,
    const float* __restrict__ fb, float* __restrict__ out, int b0)
{
    int bl = blockIdx.y;
    int t  = blockIdx.x * 256 + threadIdx.x;
    const float* hr = h + ((size_t)bl * T_LEN + t) * HP;
    float acc[C_CLS];
#pragma unroll
    for (int c = 0; c < C_CLS; ++c) acc[c] = fb[c];
#pragma unroll
    for (int qf = 0; qf < 19; ++qf) {
        float4 v = *(const float4*)(hr + qf * 4);
#pragma unroll
        for (int c = 0; c < C_CLS; ++c) {
            const float* w = fw + c * F_CH + qf * 4;
            acc[c] = fmaf(w[0], v.x, acc[c]);
            acc[c] = fmaf(w[1], v.y, acc[c]);
            acc[c] = fmaf(w[2], v.z, acc[c]);
            acc[c] = fmaf(w[3], v.w, acc[c]);
        }
    }
    float* ob = out + ((size_t)(b0 + bl) * T_LEN + t) * C_CLS;
#pragma unroll
    for (int c = 0; c < C_CLS; ++c) ob[c] = acc[c];
}

extern "C" void kernel_launch(void* const* d_in, const int* in_sizes, int n_in,
                              void* d_out, int out_size, void* d_ws, size_t ws_size,
                              hipStream_t stream)
{
    const float* x  = (const float*)d_in[0];
    const float* cw = (const float*)d_in[1];
    const float* cb = (const float*)d_in[2];
    const float* fw = (const float*)d_in[3];
    const float* fb = (const float*)d_in[4];
    float* out = (float*)d_out;

    const size_t FT = (size_t)T_LEN * HP;            // floats per batch plane

    __bf16* WPB = (__bf16*)d_ws;
    const size_t wpbFloats = 12800;                  // 3*96*88 bf16, padded
    float* planes = (float*)d_ws + wpbFloats;

    size_t planeBytes = 2 * FT * sizeof(float);
    size_t avail = ws_size - wpbFloats * sizeof(float);
    int Bc = (int)(avail / planeBytes);
    if (Bc > B_TOT) Bc = B_TOT;
    if (Bc < 1) Bc = 1;

    float* H0 = planes;
    float* H1 = H0 + (size_t)Bc * FT;

    wprep_kernel<<<(3 * 96 * WSTR + 255) / 256, 256, 0, stream>>>(cw, WPB);

    for (int b0 = 0; b0 < B_TOT; b0 += Bc) {
        int bc = (B_TOT - b0 < Bc) ? (B_TOT - b0) : Bc;

        dim3 gP(T_LEN * 20 / 256, bc);
        pad_copy_kernel<<<gP, 256, 0, stream>>>(x, H0, b0);

        float* hcur = H0;
        float* hnxt = H1;
        dim3 gR(NBT, bc);
        for (int st2 = 0; st2 < NSTEP / 2; ++st2) {
            rk4_step2_kernel<<<gR, TPB, 0, stream>>>(hcur, hnxt, WPB, cb);
            float* tmp = hcur; hcur = hnxt; hnxt = tmp;
        }

        dim3 gF(T_LEN / 256, bc);
        final_kernel<<<gF, 256, 0, stream>>>(hcur, fw, fb, out, b0);
    }
}